// Round 4
// baseline (282.582 us; speedup 1.0000x reference)
//
#include <hip/hip_runtime.h>
#include <hip/hip_bf16.h>
#include <stdint.h>

// Problem constants
#define M_DIM 32768
#define N_DIM 1024
#define K_DIM 1024

using int32x4 = __attribute__((ext_vector_type(4))) int;

__device__ __forceinline__ void gload_lds16(const void* g, void* l) {
  __builtin_amdgcn_global_load_lds(
      (const __attribute__((address_space(1))) void*)g,
      (__attribute__((address_space(3))) void*)l,
      16 /*bytes*/, 0 /*offset*/, 0 /*aux*/);
}

// ---------------- Kernel 1: fused weight-unpack + activation-quantize ----------------
// Blocks [0,512): unpack int4 weights -> int8 [N, K].
//   HARNESS NOTE: integer inputs arrive as int32 — weight_packed is 524288 int32
//   elements, ONE packed byte (0..255) per int32. Byte j of row r: low nibble ->
//   w[r][2j], high nibble -> w[r][2j+1]. sext4(v) = ((v&0xF)^8)-8.
// Blocks [512, 33280): quantize fp32 x -> int8: clip(rint(x*20), -127, 127).
__global__ __launch_bounds__(256) void prep_kernel(const float* __restrict__ x,
                                                   const int4* __restrict__ wp,
                                                   uint32_t* __restrict__ q,
                                                   uint2* __restrict__ w8) {
  const int bx = blockIdx.x;
  const int tid = threadIdx.x;
  if (bx < 512) {
    const int g = bx * 256 + tid;  // 4 packed bytes -> 8 int8
    const int4 p = wp[g];
    int w0 = ((p.x & 0xF) ^ 8) - 8;
    int w1 = (((p.x >> 4) & 0xF) ^ 8) - 8;
    int w2 = ((p.y & 0xF) ^ 8) - 8;
    int w3 = (((p.y >> 4) & 0xF) ^ 8) - 8;
    int w4 = ((p.z & 0xF) ^ 8) - 8;
    int w5 = (((p.z >> 4) & 0xF) ^ 8) - 8;
    int w6 = ((p.w & 0xF) ^ 8) - 8;
    int w7 = (((p.w >> 4) & 0xF) ^ 8) - 8;
    uint2 st;
    st.x = (uint32_t)(w0 & 0xFF) | ((uint32_t)(w1 & 0xFF) << 8) |
           ((uint32_t)(w2 & 0xFF) << 16) | ((uint32_t)(w3 & 0xFF) << 24);
    st.y = (uint32_t)(w4 & 0xFF) | ((uint32_t)(w5 & 0xFF) << 8) |
           ((uint32_t)(w6 & 0xFF) << 16) | ((uint32_t)(w7 & 0xFF) << 24);
    w8[g] = st;
  } else {
    const int g = (bx - 512) * 256 + tid;  // one float4 per thread
    const float4 v = ((const float4*)x)[g];
    int a0 = (int)rintf(fminf(fmaxf(v.x * 20.0f, -127.0f), 127.0f));
    int a1 = (int)rintf(fminf(fmaxf(v.y * 20.0f, -127.0f), 127.0f));
    int a2 = (int)rintf(fminf(fmaxf(v.z * 20.0f, -127.0f), 127.0f));
    int a3 = (int)rintf(fminf(fmaxf(v.w * 20.0f, -127.0f), 127.0f));
    q[g] = (uint32_t)(a0 & 0xFF) | ((uint32_t)(a1 & 0xFF) << 8) |
           ((uint32_t)(a2 & 0xFF) << 16) | ((uint32_t)(a3 & 0xFF) << 24);
  }
}

// ---------------- Kernel 2: int8 x int8 GEMM with dequant epilogue ----------------
// C[m][n] = (sum_k A[m][k] * W[n][k]) * (A_SCALE*W_SCALE) + bias[n], f32 out.
// 128x128 tile, BK=64, 4 waves in 2x2, mfma_i32_16x16x64_i8.
// Double-buffered LDS, ONE barrier per K-iter: at the barrier of iter k,
// tile k's loads (issued during iter k-1's compute) drain nearly-free, and
// every wave has finished computing from buf[(k-1)&1] — so prefetching tile
// k+1 into that buffer right after the barrier is race-free and overlaps the
// global->LDS latency with this iter's MFMA.
// LDS chunk swizzle: LDS[r][c] = G[r][c ^ ((r>>1)&3)] -> frag ds_read_b128
// covers all 32 banks exactly once per 8-lane phase (conflict-free).
__global__ __launch_bounds__(256) void gemm_kernel(const uint8_t* __restrict__ A,
                                                   const uint8_t* __restrict__ W,
                                                   const float* __restrict__ bias,
                                                   float* __restrict__ out) {
  __shared__ uint8_t sA[2][128 * 64];
  __shared__ uint8_t sB[2][128 * 64];

  const int tid = threadIdx.x;
  const int bx = blockIdx.x;
  const int n0 = (bx & 7) * 128;   // N/128 = 8 fastest -> concurrent blocks share A row-tile
  const int m0 = (bx >> 3) * 128;
  const int lane = tid & 63;
  const int wid = tid >> 6;
  const int wm = wid >> 1;
  const int wn = wid & 1;

  // Staging: 8 KB per tile = 512 chunks of 16 B; 256 threads x 2 chunks.
  // li = j*256 + tid; row r = li>>2; lds slot c = li&3; global chunk cg = c ^ ((r>>1)&3)
  const int li0 = tid, li1 = 256 + tid;
  const int r0 = li0 >> 2, c0 = li0 & 3;
  const int r1 = li1 >> 2, c1 = li1 & 3;
  const int cg0 = c0 ^ ((r0 >> 1) & 3);
  const int cg1 = c1 ^ ((r1 >> 1) & 3);
  const uint8_t* gA0 = A + (size_t)(m0 + r0) * K_DIM + cg0 * 16;
  const uint8_t* gA1 = A + (size_t)(m0 + r1) * K_DIM + cg1 * 16;
  const uint8_t* gB0 = W + (size_t)(n0 + r0) * K_DIM + cg0 * 16;
  const uint8_t* gB1 = W + (size_t)(n0 + r1) * K_DIM + cg1 * 16;

  // Prologue: tile 0 -> buffer 0
  gload_lds16(gA0, sA[0] + li0 * 16);
  gload_lds16(gA1, sA[0] + li1 * 16);
  gload_lds16(gB0, sB[0] + li0 * 16);
  gload_lds16(gB1, sB[0] + li1 * 16);

  int32x4 acc[4][4] = {};  // 64 accumulator regs

  const int q = lane >> 4;          // logical 16-byte chunk (k-quarter) for frags
  const int fr = lane & 15;         // row/col within 16-tile

#pragma unroll 1
  for (int kk = 0; kk < 16; kk++) {
    __syncthreads();  // tile kk visible; all waves done with buf[(kk-1)&1]

    if (kk < 15) {  // prefetch tile kk+1 into the other buffer (flies during MFMA)
      const int off = (kk + 1) * 64;
      const int nb = (kk + 1) & 1;
      gload_lds16(gA0 + off, sA[nb] + li0 * 16);
      gload_lds16(gA1 + off, sA[nb] + li1 * 16);
      gload_lds16(gB0 + off, sB[nb] + li0 * 16);
      gload_lds16(gB1 + off, sB[nb] + li1 * 16);
    }

    const uint8_t* pA = sA[kk & 1];
    const uint8_t* pB = sB[kk & 1];

    int32x4 af[4], bf[4];
#pragma unroll
    for (int mt = 0; mt < 4; mt++) {
      const int r = wm * 64 + mt * 16 + fr;
      const int cc = q ^ ((r >> 1) & 3);
      af[mt] = *(const int32x4*)(pA + r * 64 + cc * 16);
    }
#pragma unroll
    for (int nt = 0; nt < 4; nt++) {
      const int r = wn * 64 + nt * 16 + fr;
      const int cc = q ^ ((r >> 1) & 3);
      bf[nt] = *(const int32x4*)(pB + r * 64 + cc * 16);
    }
#pragma unroll
    for (int mt = 0; mt < 4; mt++)
#pragma unroll
      for (int nt = 0; nt < 4; nt++)
        acc[mt][nt] = __builtin_amdgcn_mfma_i32_16x16x64_i8(af[mt], bf[nt], acc[mt][nt], 0, 0, 0);
  }

  // Epilogue: C/D layout col = lane&15, row = (lane>>4)*4 + reg
  float bv[4];
#pragma unroll
  for (int nt = 0; nt < 4; nt++) bv[nt] = bias[n0 + wn * 64 + nt * 16 + fr];

  const int rowq = (lane >> 4) * 4;
#pragma unroll
  for (int mt = 0; mt < 4; mt++) {
#pragma unroll
    for (int nt = 0; nt < 4; nt++) {
      const int n_g = n0 + wn * 64 + nt * 16 + fr;
#pragma unroll
      for (int r = 0; r < 4; r++) {
        const int m_g = m0 + wm * 64 + mt * 16 + rowq + r;
        const float v = (float)acc[mt][nt][r] * 0.0005f + bv[nt];
        // Output is write-once, never re-read: keep it out of L2/LLC.
        __builtin_nontemporal_store(v, &out[(size_t)m_g * N_DIM + n_g]);
      }
    }
  }
}

extern "C" void kernel_launch(void* const* d_in, const int* in_sizes, int n_in,
                              void* d_out, int out_size, void* d_ws, size_t ws_size,
                              hipStream_t stream) {
  const float* x = (const float*)d_in[0];
  const int4* wp = (const int4*)d_in[1];   // int32 per packed byte (harness int rule)
  const float* bias = (const float*)d_in[2];
  float* out = (float*)d_out;

  uint8_t* A8 = (uint8_t*)d_ws;                       // 32768*1024 int8 = 32 MiB
  uint8_t* W8 = A8 + (size_t)M_DIM * K_DIM;           // 1024*1024 int8 = 1 MiB

  // K1: fused unpack (512 blocks) + quantize (32768 blocks)
  prep_kernel<<<512 + (M_DIM * K_DIM) / (4 * 256), 256, 0, stream>>>(
      x, wp, (uint32_t*)A8, (uint2*)W8);
  // K2: GEMM. grid = (M/128)*(N/128) = 2048
  gemm_kernel<<<(M_DIM / 128) * (N_DIM / 128), 256, 0, stream>>>(A8, W8, bias, out);
}

// Round 5
// 261.150 us; speedup vs baseline: 1.0821x; 1.0821x over previous
//
#include <hip/hip_runtime.h>
#include <hip/hip_bf16.h>
#include <stdint.h>

// Problem constants
#define M_DIM 32768
#define N_DIM 1024
#define K_DIM 1024

using int32x4 = __attribute__((ext_vector_type(4))) int;
using int32x16 = __attribute__((ext_vector_type(16))) int;

__device__ __forceinline__ void gload_lds16(const void* g, void* l) {
  __builtin_amdgcn_global_load_lds(
      (const __attribute__((address_space(1))) void*)g,
      (__attribute__((address_space(3))) void*)l,
      16 /*bytes*/, 0 /*offset*/, 0 /*aux*/);
}

// ---------------- Kernel 1: fused weight-unpack + activation-quantize ----------------
// Blocks [0,512): unpack int4 weights -> int8 [N, K].
//   HARNESS NOTE: integer inputs arrive as int32 — weight_packed is 524288 int32
//   elements, ONE packed byte (0..255) per int32. Byte j of row r: low nibble ->
//   w[r][2j], high nibble -> w[r][2j+1]. sext4(v) = ((v&0xF)^8)-8.
// Blocks [512, 33280): quantize fp32 x -> int8: clip(rint(x*20), -127, 127).
__global__ __launch_bounds__(256) void prep_kernel(const float* __restrict__ x,
                                                   const int4* __restrict__ wp,
                                                   uint32_t* __restrict__ q,
                                                   uint2* __restrict__ w8) {
  const int bx = blockIdx.x;
  const int tid = threadIdx.x;
  if (bx < 512) {
    const int g = bx * 256 + tid;  // 4 packed bytes -> 8 int8
    const int4 p = wp[g];
    int w0 = ((p.x & 0xF) ^ 8) - 8;
    int w1 = (((p.x >> 4) & 0xF) ^ 8) - 8;
    int w2 = ((p.y & 0xF) ^ 8) - 8;
    int w3 = (((p.y >> 4) & 0xF) ^ 8) - 8;
    int w4 = ((p.z & 0xF) ^ 8) - 8;
    int w5 = (((p.z >> 4) & 0xF) ^ 8) - 8;
    int w6 = ((p.w & 0xF) ^ 8) - 8;
    int w7 = (((p.w >> 4) & 0xF) ^ 8) - 8;
    uint2 st;
    st.x = (uint32_t)(w0 & 0xFF) | ((uint32_t)(w1 & 0xFF) << 8) |
           ((uint32_t)(w2 & 0xFF) << 16) | ((uint32_t)(w3 & 0xFF) << 24);
    st.y = (uint32_t)(w4 & 0xFF) | ((uint32_t)(w5 & 0xFF) << 8) |
           ((uint32_t)(w6 & 0xFF) << 16) | ((uint32_t)(w7 & 0xFF) << 24);
    w8[g] = st;
  } else {
    const int g = (bx - 512) * 256 + tid;  // one float4 per thread
    const float4 v = ((const float4*)x)[g];
    int a0 = (int)rintf(fminf(fmaxf(v.x * 20.0f, -127.0f), 127.0f));
    int a1 = (int)rintf(fminf(fmaxf(v.y * 20.0f, -127.0f), 127.0f));
    int a2 = (int)rintf(fminf(fmaxf(v.z * 20.0f, -127.0f), 127.0f));
    int a3 = (int)rintf(fminf(fmaxf(v.w * 20.0f, -127.0f), 127.0f));
    q[g] = (uint32_t)(a0 & 0xFF) | ((uint32_t)(a1 & 0xFF) << 8) |
           ((uint32_t)(a2 & 0xFF) << 16) | ((uint32_t)(a3 & 0xFF) << 24);
  }
}

// ---------------- Kernel 2: int8 GEMM, producer/consumer wave specialization ----------
// C[m][n] = (sum_k A[m][k]*W[n][k]) * 5e-4 + bias[n], f32 out.
// Block = 320 threads: waves 0..3 = consumers (2x2 grid of 64x64 sub-tiles,
// mfma_i32_32x32x32_i8), wave 4 = producer (global_load_lds staging only).
// 3 LDS buffers, prefetch distance 2. Producer waits vmcnt(16) (= newest tile
// may stay in flight) before each s_barrier; consumer waves issue NO vm ops in
// the loop, so the compiler cannot insert a defeating vmcnt(0) before their
// ds_reads. This is the AITER-style K-loop the m97 2-barrier shape can't express.
// LDS chunk swizzle: LDS[r][c] = G[r][c ^ ((r>>1)&3)] (16B chunks) -> frag
// ds_read_b128 lands 2-way bank aliasing (free), staging stays lane-contiguous.
// Grid swizzle: bx&7 = XCD (round-robin dispatch) owns m-tiles [32x,32x+32) so
// each A line is L2-filled on exactly one XCD; the 8 n-blocks sharing an m-tile
// are co-resident there -> ~1x A fabric traffic.
__global__ __launch_bounds__(320, 3) void gemm_kernel(const uint8_t* __restrict__ A,
                                                      const uint8_t* __restrict__ W,
                                                      const float* __restrict__ bias,
                                                      float* __restrict__ out) {
  __shared__ uint8_t sA[3][128 * 64];
  __shared__ uint8_t sB[3][128 * 64];

  const int tid = threadIdx.x;
  const int bx = blockIdx.x;
  const int xcd = bx & 7;
  const int tt = bx >> 3;
  const int m0 = (xcd * 32 + (tt >> 3)) * 128;
  const int n0 = (tt & 7) * 128;

  if (tid >= 256) {
    // ================= producer wave =================
    const int lane = tid - 256;
    const uint8_t* gA[8];
    const uint8_t* gB[8];
    uint32_t lofs[8];
#pragma unroll
    for (int j = 0; j < 8; j++) {
      const int li = j * 64 + lane;      // chunk id within 512-chunk tile
      const int r = li >> 2, c = li & 3; // row, LDS slot
      const int cg = c ^ ((r >> 1) & 3); // swizzled global 16B chunk
      gA[j] = A + (size_t)(m0 + r) * K_DIM + cg * 16;
      gB[j] = W + (size_t)(n0 + r) * K_DIM + cg * 16;
      lofs[j] = (uint32_t)li * 16;
    }
    // Prologue: tile 0 -> buf0, tile 1 -> buf1 (16 loads each, 32 in flight)
#pragma unroll
    for (int j = 0; j < 8; j++) gload_lds16(gA[j], &sA[0][0] + lofs[j]);
#pragma unroll
    for (int j = 0; j < 8; j++) gload_lds16(gB[j], &sB[0][0] + lofs[j]);
#pragma unroll
    for (int j = 0; j < 8; j++) gload_lds16(gA[j] + 64, &sA[1][0] + lofs[j]);
#pragma unroll
    for (int j = 0; j < 8; j++) gload_lds16(gB[j] + 64, &sB[1][0] + lofs[j]);

    int pbo = 2 * 8192;  // buffer byte-offset for tile kk+2
#pragma unroll 1
    for (int kk = 0; kk < 15; kk++) {
      // Tile kk complete (allow tile kk+1's 16 loads to stay in flight), then barrier.
      asm volatile("s_waitcnt vmcnt(16)\n\ts_barrier" ::: "memory");
      if (kk < 14) {
        const int off = (kk + 2) * 64;
#pragma unroll
        for (int j = 0; j < 8; j++) gload_lds16(gA[j] + off, &sA[0][0] + pbo + lofs[j]);
#pragma unroll
        for (int j = 0; j < 8; j++) gload_lds16(gB[j] + off, &sB[0][0] + pbo + lofs[j]);
        pbo = (pbo == 16384) ? 0 : pbo + 8192;
      }
    }
    asm volatile("s_waitcnt vmcnt(0)\n\ts_barrier" ::: "memory");  // tile 15 landed
    // producer done (16 barriers total, matching consumers)
  } else {
    // ================= consumer waves =================
    const int lane = tid & 63;
    const int wid = tid >> 6;   // 0..3
    const int wm = wid >> 1;    // m-half of 128-tile
    const int wn = wid & 1;     // n-half
    const int rl = lane & 31;   // row/col within 32-tile
    const int hl = lane >> 5;   // k-half selector

    // Fragment LDS byte offsets (A: rows m, B: rows n), swizzle-corrected.
    uint32_t offA[2][2], offB[2][2];
#pragma unroll
    for (int mt = 0; mt < 2; mt++)
#pragma unroll
      for (int ks = 0; ks < 2; ks++) {
        const int rA = wm * 64 + mt * 32 + rl;
        const int ccA = (ks * 2 + hl) ^ ((rA >> 1) & 3);
        offA[mt][ks] = (uint32_t)(rA * 64 + ccA * 16);
        const int rB = wn * 64 + mt * 32 + rl;
        const int ccB = (ks * 2 + hl) ^ ((rB >> 1) & 3);
        offB[mt][ks] = (uint32_t)(rB * 64 + ccB * 16);
      }

    int32x16 acc[2][2] = {};
    int cbo = 0;  // compute-buffer byte offset
#pragma unroll 1
    for (int kk = 0; kk < 16; kk++) {
      asm volatile("s_barrier" ::: "memory");  // tile kk visible (producer waited vmcnt)
      const uint8_t* pA = &sA[0][0] + cbo;
      const uint8_t* pB = &sB[0][0] + cbo;
#pragma unroll
      for (int ks = 0; ks < 2; ks++) {
        int32x4 a0 = *(const int32x4*)(pA + offA[0][ks]);
        int32x4 a1 = *(const int32x4*)(pA + offA[1][ks]);
        int32x4 b0 = *(const int32x4*)(pB + offB[0][ks]);
        int32x4 b1 = *(const int32x4*)(pB + offB[1][ks]);
        acc[0][0] = __builtin_amdgcn_mfma_i32_32x32x32_i8(a0, b0, acc[0][0], 0, 0, 0);
        acc[0][1] = __builtin_amdgcn_mfma_i32_32x32x32_i8(a0, b1, acc[0][1], 0, 0, 0);
        acc[1][0] = __builtin_amdgcn_mfma_i32_32x32x32_i8(a1, b0, acc[1][0], 0, 0, 0);
        acc[1][1] = __builtin_amdgcn_mfma_i32_32x32x32_i8(a1, b1, acc[1][1], 0, 0, 0);
      }
      cbo = (cbo == 16384) ? 0 : cbo + 8192;
    }

    // Epilogue. 32x32 C/D layout: col = lane&31, row = (reg&3) + 8*(reg>>2) + 4*(lane>>5).
    float bv[2];
#pragma unroll
    for (int nt = 0; nt < 2; nt++) bv[nt] = bias[n0 + wn * 64 + nt * 32 + rl];

#pragma unroll
    for (int mt = 0; mt < 2; mt++) {
#pragma unroll
      for (int nt = 0; nt < 2; nt++) {
        const int n_g = n0 + wn * 64 + nt * 32 + rl;
        const int mbase = m0 + wm * 64 + mt * 32 + 4 * hl;
#pragma unroll
        for (int reg = 0; reg < 16; reg++) {
          const int m_g = mbase + (reg & 3) + 8 * (reg >> 2);
          const float v = (float)acc[mt][nt][reg] * 0.0005f + bv[nt];
          // lanes 0..31 cover 32 consecutive n -> full 128B lines; write-once data.
          __builtin_nontemporal_store(v, &out[(size_t)m_g * N_DIM + n_g]);
        }
      }
    }
  }
}

extern "C" void kernel_launch(void* const* d_in, const int* in_sizes, int n_in,
                              void* d_out, int out_size, void* d_ws, size_t ws_size,
                              hipStream_t stream) {
  const float* x = (const float*)d_in[0];
  const int4* wp = (const int4*)d_in[1];   // int32 per packed byte (harness int rule)
  const float* bias = (const float*)d_in[2];
  float* out = (float*)d_out;

  uint8_t* A8 = (uint8_t*)d_ws;                       // 32768*1024 int8 = 32 MiB
  uint8_t* W8 = A8 + (size_t)M_DIM * K_DIM;           // 1024*1024 int8 = 1 MiB

  // K1: fused unpack (512 blocks) + quantize (32768 blocks)
  prep_kernel<<<512 + (M_DIM * K_DIM) / (4 * 256), 256, 0, stream>>>(
      x, wp, (uint32_t*)A8, (uint2*)W8);
  // K2: GEMM. grid = (M/128)*(N/128) = 2048, 320 threads (4 consumer + 1 producer waves)
  gemm_kernel<<<(M_DIM / 128) * (N_DIM / 128), 320, 0, stream>>>(A8, W8, bias, out);
}